// Round 6
// baseline (66.079 us; speedup 1.0000x reference)
//
#include <hip/hip_runtime.h>
#include <hip/hip_fp16.h>

typedef _Float16 f16x2 __attribute__((ext_vector_type(2)));
typedef _Float16 f16x8 __attribute__((ext_vector_type(8)));
typedef float    f32x4 __attribute__((ext_vector_type(4)));

#define M_DIM   32
#define K_DIM   8192
#define N_DIM   28672
#define KWORDS  1024           // K/8 packed words per weight row
#define NKB     128            // K/64 scale blocks per row
#define NBLK_N  448            // N/64 n-blocks
#define NSPLIT  8
#define NSB     8              // 128-k superblocks per chunk (KCHUNK=1024)
#define OUT_ELEMS (M_DIM * N_DIM)
#define X16_BYTES (KWORDS * M_DIM * 16)   // 512 KB permuted-fp16 x

__device__ __forceinline__ unsigned pkrtz(float a, float b) {
    return __builtin_bit_cast(unsigned, __builtin_amdgcn_cvt_pkrtz(a, b));
}

// ---- x -> fragment-layout fp16: x16[w][m] = 8 fp16, pairs (k=8w+p, 8w+p+4)
// (identical k-permutation to the nibble unpack, so MFMA k-sums match)
__global__ __launch_bounds__(256) void x_transform(const float* __restrict__ x,
                                                   uint4* __restrict__ x16) {
    const int idx = blockIdx.x * 256 + threadIdx.x;   // w*32 + m
    const int w = idx >> 5, m = idx & 31;
    const float4* p = (const float4*)(x + (size_t)m * K_DIM + w * 8);
    float4 f0 = p[0], f1 = p[1];
    uint4 v = { pkrtz(f0.x, f1.x), pkrtz(f0.y, f1.y),
                pkrtz(f0.z, f1.z), pkrtz(f0.w, f1.w) };
    x16[idx] = v;
}

// ---- atomic-fallback init: out[m,n] = bias[n] ----
__global__ __launch_bounds__(256) void wql_init(const float* __restrict__ bias,
                                                float* __restrict__ out) {
    int n = blockIdx.x * 256 + threadIdx.x;
    int m = blockIdx.y;
    out[(size_t)m * N_DIM + n] = bias[n];
}

// 8 nibbles -> 8 dequantized fp16. Pair p = nibbles (p,p+4); 0x6400|q = 1024+q
// exact; cpk = -(1024+8+zq) exact; (f+cpk) is an exact small int in fp16,
// one rounding on *spk.
__device__ __forceinline__ f16x8 dq_word(unsigned W, f16x2 spk, f16x2 cpk) {
    union { f16x2 h[4]; f16x8 v; } r;
#pragma unroll
    for (int p = 0; p < 4; ++p) {
        unsigned raw = ((W >> (4 * p)) & 0x000F000Fu) | 0x64006400u;
        f16x2 f = __builtin_bit_cast(f16x2, raw);
        r.h[p] = (f + cpk) * spk;
    }
    return r.v;
}

// 256 thr / 4 waves, n-tile 64 (16 n per wave), all of M=32, KCHUNK=1024.
// NO LDS, NO barriers: B-frags are global-loaded from the pre-permuted x16
// (512 KB, L2-resident chip-wide), qweight/scales/zeros hoisted per wave.
// Waves free-run -> continuous VMEM issue; occupancy capped by VGPR only.
template <bool ATOMIC>
__global__ __launch_bounds__(256, 4) void wql_main(
    const uint4* __restrict__ x16, const unsigned* __restrict__ qw,
    const float* __restrict__ scales, const unsigned* __restrict__ qzeros,
    float* __restrict__ outp)
{
    const int tid  = threadIdx.x;
    const int bid  = blockIdx.x;
    const int nblk = bid % NBLK_N;
    const int ks   = bid / NBLK_N;
    const int n0   = nblk * 64;
    const int kw0  = ks * (NSB * 16);     // first packed word of this chunk

    const int wv   = tid >> 6;            // 0..3
    const int lane = tid & 63;
    const int g    = lane >> 4;           // k-group
    const int lr   = lane & 15;           // A-row (n) / B-col (m)
    const int gh   = g >> 1;
    const int n_row = n0 + wv * 16 + lr;

    // ---- hoisted qweight stream: lane g owns words 16s+4g..+3 per section s
    uint4 wq[NSB];
    const uint4* qp = (const uint4*)(qw + (size_t)n_row * KWORDS + kw0);
#pragma unroll
    for (int s = 0; s < NSB; ++s) wq[s] = qp[4 * s + g];

    // ---- scales: 16 per row-chunk ----
    f32x4 s4[4];
    const f32x4* srow = (const f32x4*)(scales + (size_t)n_row * NKB + ks * 16);
#pragma unroll
    for (int i = 0; i < 4; ++i) s4[i] = srow[i];

    // ---- zeros: 16 nibbles = 2 words ----
    uint2 zw = *(const uint2*)(qzeros + (size_t)n_row * (NKB / 8) + ks * 2);
    unsigned zwv[2] = { zw.x, zw.y };

    const uint4* xw = x16 + (size_t)kw0 * 32;   // this chunk's fragments

    f32x4 acc0 = {0.f, 0.f, 0.f, 0.f};
    f32x4 acc1 = {0.f, 0.f, 0.f, 0.f};

#pragma unroll
    for (int sb = 0; sb < NSB; ++sb) {
        // scale block within chunk = 2*sb + gh
        const int zq = (zwv[(2 * sb) >> 3] >> (4 * ((2 * sb + gh) & 7))) & 0xF;
        const float sf = s4[sb >> 1][(sb & 1) * 2 + gh];
        const _Float16 sh = (_Float16)sf;
        const _Float16 ch = (_Float16)(-(float)(1032 + zq));
        const f16x2 spk = { sh, sh };
        const f16x2 cpk = { ch, ch };
        const unsigned wa[4] = { wq[sb].x, wq[sb].y, wq[sb].z, wq[sb].w };
#pragma unroll
        for (int j = 0; j < 4; ++j) {
            const int w = 16 * sb + 4 * g + j;          // chunk-local word
            f16x8 b0 = __builtin_bit_cast(f16x8, xw[w * 32 + lr]);
            f16x8 b1 = __builtin_bit_cast(f16x8, xw[w * 32 + lr + 16]);
            f16x8 a  = dq_word(wa[j], spk, cpk);
            acc0 = __builtin_amdgcn_mfma_f32_16x16x32_f16(a, b0, acc0, 0, 0, 0);
            acc1 = __builtin_amdgcn_mfma_f32_16x16x32_f16(a, b1, acc1, 0, 0, 0);
        }
    }

    // C/D: col(m) = lane&15, n-within-16 = 4*(lane>>4)+reg
    const size_t obase = (size_t)lr * N_DIM + n0 + wv * 16 + 4 * g;
    if constexpr (ATOMIC) {
#pragma unroll
        for (int r = 0; r < 4; ++r) {
            atomicAdd(outp + obase + r, acc0[r]);
            atomicAdd(outp + obase + (size_t)16 * N_DIM + r, acc1[r]);
        }
    } else {
        float* dst = outp + (size_t)ks * OUT_ELEMS;
        *(f32x4*)(dst + obase) = acc0;
        *(f32x4*)(dst + obase + (size_t)16 * N_DIM) = acc1;
    }
}

// out = bias + sum of 8 split partials (partials L3-hot right after main)
__global__ __launch_bounds__(256) void wql_reduce(const float* __restrict__ ws,
                                                  const float* __restrict__ bias,
                                                  float* __restrict__ out) {
    const int i4 = (blockIdx.x * 256 + threadIdx.x) * 4;
    const int n  = i4 % N_DIM;
    f32x4 acc = *(const f32x4*)(bias + n);
#pragma unroll
    for (int s = 0; s < NSPLIT; ++s)
        acc += *(const f32x4*)(ws + (size_t)s * OUT_ELEMS + i4);
    *(f32x4*)(out + i4) = acc;
}

extern "C" void kernel_launch(void* const* d_in, const int* in_sizes, int n_in,
                              void* d_out, int out_size, void* d_ws, size_t ws_size,
                              hipStream_t stream) {
    const float*    x      = (const float*)d_in[0];
    const unsigned* qwght  = (const unsigned*)d_in[1];
    const float*    scales = (const float*)d_in[2];
    const unsigned* qzeros = (const unsigned*)d_in[3];
    const float*    bias   = (const float*)d_in[4];
    float* out = (float*)d_out;

    uint4* x16 = (uint4*)d_ws;
    float* part = (float*)((char*)d_ws + X16_BYTES);
    const size_t need = X16_BYTES + (size_t)NSPLIT * OUT_ELEMS * sizeof(float);

    x_transform<<<dim3(KWORDS * M_DIM / 256), 256, 0, stream>>>(x, x16);
    if (ws_size >= need) {
        // K-split partials -> ws (no atomics), then reduce
        wql_main<false><<<dim3(NBLK_N * NSPLIT), 256, 0, stream>>>(
            x16, qwght, scales, qzeros, part);
        wql_reduce<<<dim3(OUT_ELEMS / 1024), 256, 0, stream>>>(
            part, bias, out);
    } else {
        // fallback: atomics onto bias-initialized out
        wql_init<<<dim3(N_DIM / 256, M_DIM), 256, 0, stream>>>(bias, out);
        wql_main<true><<<dim3(NBLK_N * NSPLIT), 256, 0, stream>>>(
            x16, qwght, scales, qzeros, out);
    }
}

// Round 7
// 51.710 us; speedup vs baseline: 1.2779x; 1.2779x over previous
//
#include <hip/hip_runtime.h>
#include <hip/hip_fp16.h>

typedef _Float16 f16x2 __attribute__((ext_vector_type(2)));
typedef _Float16 f16x8 __attribute__((ext_vector_type(8)));
typedef float    f32x4 __attribute__((ext_vector_type(4)));
typedef unsigned u32x4 __attribute__((ext_vector_type(4)));
typedef unsigned u32x2 __attribute__((ext_vector_type(2)));

#define M_DIM   32
#define K_DIM   8192
#define N_DIM   28672
#define KWORDS  1024           // K/8 packed words per weight row
#define NKB     128            // K/64 scale blocks per row
#define NBLK_N  224            // N/128 n-blocks
#define NSPLIT  8
#define NSB     8              // 128-k superblocks per chunk (KCHUNK=1024)
#define OUT_ELEMS (M_DIM * N_DIM)
#define X16_BYTES (KWORDS * M_DIM * 16)   // 512 KB fragment-layout x

__device__ __forceinline__ unsigned pkrtz(float a, float b) {
    return __builtin_bit_cast(unsigned, __builtin_amdgcn_cvt_pkrtz(a, b));
}

// x -> fragment-layout fp16: x16[w][m] = 8 fp16, pairs (k=8w+p, 8w+p+4)
// (identical k-permutation to the nibble unpack, so MFMA k-sums match)
__global__ __launch_bounds__(256) void x_transform(const float* __restrict__ x,
                                                   uint4* __restrict__ x16) {
    const int idx = blockIdx.x * 256 + threadIdx.x;   // w*32 + m
    const int w = idx >> 5, m = idx & 31;
    const float4* p = (const float4*)(x + (size_t)m * K_DIM + w * 8);
    float4 f0 = p[0], f1 = p[1];
    uint4 v = { pkrtz(f0.x, f1.x), pkrtz(f0.y, f1.y),
                pkrtz(f0.z, f1.z), pkrtz(f0.w, f1.w) };
    x16[idx] = v;
}

__global__ __launch_bounds__(256) void wql_init(const float* __restrict__ bias,
                                                float* __restrict__ out) {
    int n = blockIdx.x * 256 + threadIdx.x;
    int m = blockIdx.y;
    out[(size_t)m * N_DIM + n] = bias[n];
}

// 8 nibbles -> 8 dequantized fp16. Pair p = nibbles (p,p+4); 0x6400|q = 1024+q
// exact; cpk = -(1024+8+zq) exact int; (f+cpk) exact; one rounding on *spk.
// (Folding c*s into a pk_fma was analyzed and REJECTED: rounding c*s gives
// ~3e-3 abs weight error, correlated per block -> ~0.15 rms output error.)
__device__ __forceinline__ f16x8 dq_word(unsigned W, f16x2 spk, f16x2 cpk) {
    union { f16x2 h[4]; f16x8 v; } r;
#pragma unroll
    for (int p = 0; p < 4; ++p) {
        unsigned raw = ((W >> (4 * p)) & 0x000F000Fu) | 0x64006400u;
        f16x2 f = __builtin_bit_cast(f16x2, raw);
        r.h[p] = (f + cpk) * spk;
    }
    return r.v;
}

// order-pinned global loads (asm volatile cannot be sunk by the scheduler)
#define GL_X4(dst, addr, OFF) \
    asm volatile("global_load_dwordx4 %0, %1, off offset:" #OFF \
                 : "=v"(dst) : "v"(addr))
#define GL_X2(dst, addr, OFF) \
    asm volatile("global_load_dwordx2 %0, %1, off offset:" #OFF \
                 : "=v"(dst) : "v"(addr))
#define WAIT_V(N) do { \
    asm volatile("s_waitcnt vmcnt(" #N ")" ::: "memory"); \
    __builtin_amdgcn_sched_barrier(0); } while (0)

// 512 thr / 8 waves, n-tile 128 (16 n per wave), all of M=32, KCHUNK=1024.
// Issue stream per thread (21 vmem ops, oldest first):
//   [5] scales x4 + zeros x1  -> wait vmcnt(16) before scale prep
//   [8] global_load_lds of x16 chunk -> wait vmcnt(8) + raw s_barrier
//   [8] qweight dwordx4       -> per-sb wait vmcnt(7-sb) inside compute
// qweight stays in flight ACROSS the barrier (no full drain anywhere).
template <bool ATOMIC>
__global__ __launch_bounds__(512, 2) void wql_main(
    const uint4* __restrict__ x16, const unsigned* __restrict__ qw,
    const float* __restrict__ scales, const unsigned* __restrict__ qzeros,
    float* __restrict__ outp)
{
    __shared__ uint4 xs[4096];           // linear copy of x16 chunk [128 w][32 m]

    const int tid  = threadIdx.x;
    const int bid  = blockIdx.x;
    const int nblk = bid % NBLK_N;
    const int ks   = bid / NBLK_N;
    const int n0   = nblk * 128;
    const int kw0  = ks * 128;           // first packed word of this chunk

    const int wv   = tid >> 6;           // 0..7
    const int lane = tid & 63;
    const int g    = lane >> 4;          // k-group 0..3
    const int lr   = lane & 15;
    const int gh   = g >> 1;
    const int n_row = n0 + wv * 16 + lr;

    // ---- group 1: scales (4x dwordx4) + zeros (1x dwordx2), oldest ----
    f32x4 s4r[4];
    u32x2 zr;
    {
        const float* sp = scales + (size_t)n_row * NKB + ks * 16;
        GL_X4(s4r[0], sp, 0);
        GL_X4(s4r[1], sp, 16);
        GL_X4(s4r[2], sp, 32);
        GL_X4(s4r[3], sp, 48);
        const unsigned* zp = qzeros + (size_t)n_row * (NKB / 8) + ks * 2;
        GL_X2(zr, zp, 0);
    }
    __builtin_amdgcn_sched_barrier(0);

    // ---- group 2: stage x16 chunk -> LDS via global_load_lds (linear) ----
    {
        const uint4* gsrc = x16 + (size_t)kw0 * 32 + tid;
#pragma unroll
        for (int i = 0; i < 8; ++i)
            __builtin_amdgcn_global_load_lds(
                (const __attribute__((address_space(1))) void*)(gsrc + i * 512),
                (__attribute__((address_space(3))) void*)(&xs[tid + i * 512]),
                16, 0, 0);
    }
    __builtin_amdgcn_sched_barrier(0);

    // ---- group 3: qweight burst, 8x dwordx4, 64B apart ----
    u32x4 wq0, wq1, wq2, wq3, wq4, wq5, wq6, wq7;
    {
        const char* qb = (const char*)(qw + (size_t)n_row * KWORDS + kw0) + g * 16;
        GL_X4(wq0, qb, 0);
        GL_X4(wq1, qb, 64);
        GL_X4(wq2, qb, 128);
        GL_X4(wq3, qb, 192);
        GL_X4(wq4, qb, 256);
        GL_X4(wq5, qb, 320);
        GL_X4(wq6, qb, 384);
        GL_X4(wq7, qb, 448);
    }
    __builtin_amdgcn_sched_barrier(0);

    // ---- scale prep (overlaps gload_lds + qweight flight) ----
    WAIT_V(16);
    f16x2 spk8[8], cpk8[8];
#pragma unroll
    for (int sb = 0; sb < 8; ++sb) {
        const int zq = (zr[sb >> 2] >> (4 * ((2 * sb + gh) & 7))) & 0xF;
        const float sf = s4r[sb >> 1][(sb & 1) * 2 + gh];
        const _Float16 sh = (_Float16)sf;
        const _Float16 ch = (_Float16)(-(float)(1032 + zq));
        spk8[sb] = (f16x2){ sh, sh };
        cpk8[sb] = (f16x2){ ch, ch };
    }

    WAIT_V(8);                            // all gload_lds done
    __builtin_amdgcn_s_barrier();
    __builtin_amdgcn_sched_barrier(0);

    f32x4 acc0 = {0.f, 0.f, 0.f, 0.f};
    f32x4 acc1 = {0.f, 0.f, 0.f, 0.f};

#define SBODY(sb, wqv, VW)                                                     \
    {                                                                          \
        WAIT_V(VW);                                                            \
        const unsigned wa[4] = { wqv[0], wqv[1], wqv[2], wqv[3] };             \
        _Pragma("unroll")                                                      \
        for (int j = 0; j < 4; ++j) {                                          \
            f16x8 a = dq_word(wa[j], spk8[sb], cpk8[sb]);                      \
            const int w = 16 * (sb) + 4 * g + j;                               \
            f16x8 b0 = __builtin_bit_cast(f16x8, xs[w * 32 + lr]);             \
            f16x8 b1 = __builtin_bit_cast(f16x8, xs[w * 32 + lr + 16]);        \
            acc0 = __builtin_amdgcn_mfma_f32_16x16x32_f16(a, b0, acc0, 0,0,0); \
            acc1 = __builtin_amdgcn_mfma_f32_16x16x32_f16(a, b1, acc1, 0,0,0); \
        }                                                                      \
    }

    SBODY(0, wq0, 7)
    SBODY(1, wq1, 6)
    SBODY(2, wq2, 5)
    SBODY(3, wq3, 4)
    SBODY(4, wq4, 3)
    SBODY(5, wq5, 2)
    SBODY(6, wq6, 1)
    SBODY(7, wq7, 0)
#undef SBODY

    // C/D: col(m) = lane&15, n-within-16 = 4*(lane>>4)+reg  (validated R1/R4/R6)
    const size_t obase = (size_t)lr * N_DIM + n0 + wv * 16 + 4 * g;
    if constexpr (ATOMIC) {
#pragma unroll
        for (int r = 0; r < 4; ++r) {
            atomicAdd(outp + obase + r, acc0[r]);
            atomicAdd(outp + obase + (size_t)16 * N_DIM + r, acc1[r]);
        }
    } else {
        float* dst = outp + (size_t)ks * OUT_ELEMS;
        *(f32x4*)(dst + obase) = acc0;
        *(f32x4*)(dst + obase + (size_t)16 * N_DIM) = acc1;
    }
}

// out = bias + sum of 8 split partials (partials L3-hot right after main)
__global__ __launch_bounds__(256) void wql_reduce(const float* __restrict__ ws,
                                                  const float* __restrict__ bias,
                                                  float* __restrict__ out) {
    const int i4 = (blockIdx.x * 256 + threadIdx.x) * 4;
    const int n  = i4 % N_DIM;
    f32x4 acc = *(const f32x4*)(bias + n);
#pragma unroll
    for (int s = 0; s < NSPLIT; ++s)
        acc += *(const f32x4*)(ws + (size_t)s * OUT_ELEMS + i4);
    *(f32x4*)(out + i4) = acc;
}

extern "C" void kernel_launch(void* const* d_in, const int* in_sizes, int n_in,
                              void* d_out, int out_size, void* d_ws, size_t ws_size,
                              hipStream_t stream) {
    const float*    x      = (const float*)d_in[0];
    const unsigned* qwght  = (const unsigned*)d_in[1];
    const float*    scales = (const float*)d_in[2];
    const unsigned* qzeros = (const unsigned*)d_in[3];
    const float*    bias   = (const float*)d_in[4];
    float* out = (float*)d_out;

    uint4* x16 = (uint4*)d_ws;
    float* part = (float*)((char*)d_ws + X16_BYTES);
    const size_t need = X16_BYTES + (size_t)NSPLIT * OUT_ELEMS * sizeof(float);

    x_transform<<<dim3(KWORDS * M_DIM / 256), 256, 0, stream>>>(x, x16);
    if (ws_size >= need) {
        wql_main<false><<<dim3(NBLK_N * NSPLIT), 512, 0, stream>>>(
            x16, qwght, scales, qzeros, part);
        wql_reduce<<<dim3(OUT_ELEMS / 1024), 256, 0, stream>>>(
            part, bias, out);
    } else {
        wql_init<<<dim3(N_DIM / 256, M_DIM), 256, 0, stream>>>(bias, out);
        wql_main<true><<<dim3(NBLK_N * NSPLIT), 512, 0, stream>>>(
            x16, qwght, scales, qzeros, out);
    }
}